// Round 9
// baseline (38.979 us; speedup 1.0000x reference)
//
#include <hip/hip_runtime.h>
#include <hip/hip_bf16.h>

#define NB 4096      // batch
#define NC 100000    // classes
#define ND 256       // feature dim
#define MOM 0.01f

#define COPY_BLOCKS  ((NC * ND / 4) / 2048)  // 3125 blocks * 2048 float4
#define CHAIN_BLOCKS (NB / 4)                // 1024 blocks, 4 waves each

typedef float f32x4 __attribute__((ext_vector_type(4)));

// Fused kernel, copy blocks FIRST (saturate BW from t=0), chain blocks last.
//  Blocks [0, COPY_BLOCKS): copy 32 aligned rows of feat -> out, skipping
//    rows whose class appears in targets (owned by chain waves).
//  Blocks [COPY_BLOCKS, +CHAIN_BLOCKS): chain path — one wave per sample;
//    chain-head waves compute the final row for their class.
//  Write sets are disjoint => no ordering needed between the two paths.
//  Policy (R6 best): normal loads for feat (~50% L3 hit), NT stores for out.
__global__ __launch_bounds__(256) void mb_fused_kernel(
        const float* __restrict__ inputs,
        const int* __restrict__ targets,
        const float* __restrict__ feat_in,
        float* __restrict__ out) {
    __shared__ int4 tg4[NB / 4];   // 16 KB, chain path
    __shared__ int flags[32];      // copy path
    int t = threadIdx.x;

    if (blockIdx.x < COPY_BLOCKS) {
        // ---- copy path ----
        int cb = blockIdx.x;
        int r0 = cb * 32;  // first of the 32 rows this block covers

        if (t < 32) flags[t] = 0;
        __syncthreads();

        // Which of our 32 rows appear in targets? 256 threads * 16 targets.
        const int4* tgg = reinterpret_cast<const int4*>(targets);
        #pragma unroll
        for (int k = 0; k < 4; ++k) {
            int4 v = tgg[t + k * 256];
            if ((unsigned)(v.x - r0) < 32u) flags[v.x - r0] = 1;
            if ((unsigned)(v.y - r0) < 32u) flags[v.y - r0] = 1;
            if ((unsigned)(v.z - r0) < 32u) flags[v.z - r0] = 1;
            if ((unsigned)(v.w - r0) < 32u) flags[v.w - r0] = 1;
        }
        __syncthreads();

        const f32x4* src = reinterpret_cast<const f32x4*>(feat_in);
        f32x4* dst = reinterpret_cast<f32x4*>(out);
        size_t base = (size_t)cb * 2048 + t;
        f32x4 v0 = src[base];
        f32x4 v1 = src[base + 256];
        f32x4 v2 = src[base + 512];
        f32x4 v3 = src[base + 768];
        f32x4 v4 = src[base + 1024];
        f32x4 v5 = src[base + 1280];
        f32x4 v6 = src[base + 1536];
        f32x4 v7 = src[base + 1792];
        int w = t >> 6;  // local row of access k is w + 4k (wave-uniform)
        if (!flags[w     ]) __builtin_nontemporal_store(v0, dst + base);
        if (!flags[w +  4]) __builtin_nontemporal_store(v1, dst + base + 256);
        if (!flags[w +  8]) __builtin_nontemporal_store(v2, dst + base + 512);
        if (!flags[w + 12]) __builtin_nontemporal_store(v3, dst + base + 768);
        if (!flags[w + 16]) __builtin_nontemporal_store(v4, dst + base + 1024);
        if (!flags[w + 20]) __builtin_nontemporal_store(v5, dst + base + 1280);
        if (!flags[w + 24]) __builtin_nontemporal_store(v6, dst + base + 1536);
        if (!flags[w + 28]) __builtin_nontemporal_store(v7, dst + base + 1792);
    } else {
        // ---- chain path ----
        // Stage all targets into LDS (256 threads * 4 int4).
        #pragma unroll
        for (int k = 0; k < 4; ++k)
            tg4[t + k * 256] =
                reinterpret_cast<const int4*>(targets)[t + k * 256];
        __syncthreads();

        const int* tg = reinterpret_cast<const int*>(tg4);
        int wave = ((blockIdx.x - COPY_BLOCKS) * 256 + t) >> 6;  // sample id
        int lane = t & 63;
        int y = tg[wave];

        // Head check: does y appear at any index < wave? (256 targets/iter)
        for (int base = 0; base < wave; base += 256) {
            int4 v = tg4[(base >> 2) + lane];
            int j0 = base + lane * 4;
            bool m = (j0 < wave && v.x == y) | (j0 + 1 < wave && v.y == y)
                   | (j0 + 2 < wave && v.z == y) | (j0 + 3 < wave && v.w == y);
            if (__ballot(m)) return;  // not the chain head
        }

        // Initial row from ORIGINAL features_memory.
        float4 row = *reinterpret_cast<const float4*>(
            feat_in + (size_t)y * ND + lane * 4);

        // Walk samples j >= wave with targets[j] == y, in index order.
        for (int base = wave & ~255; base < NB; base += 256) {
            int4 v = tg4[(base >> 2) + lane];
            int j0 = base + lane * 4;
            unsigned lm = 0;
            lm |= (j0     >= wave && v.x == y) ? 1u : 0u;
            lm |= (j0 + 1 >= wave && v.y == y) ? 2u : 0u;
            lm |= (j0 + 2 >= wave && v.z == y) ? 4u : 0u;
            lm |= (j0 + 3 >= wave && v.w == y) ? 8u : 0u;
            unsigned long long wm = __ballot(lm != 0);
            while (wm) {
                int L = __ffsll((long long)wm) - 1;
                wm &= wm - 1ull;
                unsigned lmL = (unsigned)__shfl((int)lm, L);
                while (lmL) {
                    int k = __ffs((int)lmL) - 1;
                    lmL &= lmL - 1u;
                    int jj = base + L * 4 + k;
                    float4 x = *reinterpret_cast<const float4*>(
                        inputs + (size_t)jj * ND + lane * 4);
                    row.x = fmaf(MOM, row.x, (1.0f - MOM) * x.x);
                    row.y = fmaf(MOM, row.y, (1.0f - MOM) * x.y);
                    row.z = fmaf(MOM, row.z, (1.0f - MOM) * x.z);
                    row.w = fmaf(MOM, row.w, (1.0f - MOM) * x.w);
                    float ss = row.x * row.x + row.y * row.y
                             + row.z * row.z + row.w * row.w;
                    #pragma unroll
                    for (int off = 32; off > 0; off >>= 1)
                        ss += __shfl_xor(ss, off);
                    float inv = 1.0f / sqrtf(ss);
                    row.x *= inv; row.y *= inv; row.z *= inv; row.w *= inv;
                }
            }
        }

        *reinterpret_cast<float4*>(out + (size_t)y * ND + lane * 4) = row;
    }
}

extern "C" void kernel_launch(void* const* d_in, const int* in_sizes, int n_in,
                              void* d_out, int out_size, void* d_ws, size_t ws_size,
                              hipStream_t stream) {
    const float* inputs  = (const float*)d_in[0];   // [NB, ND]
    const int*   targets = (const int*)d_in[1];     // [NB]
    const float* feat    = (const float*)d_in[2];   // [NC, ND]
    float* out = (float*)d_out;                     // [NC, ND]

    mb_fused_kernel<<<COPY_BLOCKS + CHAIN_BLOCKS, 256, 0, stream>>>(
        inputs, targets, feat, out);
}

// Round 10
// 36.092 us; speedup vs baseline: 1.0800x; 1.0800x over previous
//
#include <hip/hip_runtime.h>
#include <hip/hip_bf16.h>

#define NB 4096      // batch
#define NC 100000    // classes
#define ND 256       // feature dim
#define MOM 0.01f

#define CHAIN_BLOCKS (NB / 4)        // 1024 blocks, 4 waves each = 4096 waves
#define COPY_BLOCKS  ((NC * ND / 4) / 2048)  // 3125 blocks * 2048 float4

typedef float f32x4 __attribute__((ext_vector_type(4)));

// Fused kernel (R6 structure: chain blocks first, then copy blocks).
//  Chain path: one wave per sample; chain-head waves compute the final row
//    for their class and write it. Copy path: copy 32 aligned rows of
//    feat -> out, skipping rows owned by chain waves (disjoint write sets).
//  Copy path is restructured for MLP=8: all 8 data loads are issued BEFORE
//  the target scan and pinned live across it with an asm register pin, so
//  LLVM cannot sink each load into its conditional store (R9 evidence:
//  VGPR=24 proved loads were serialized into load->wait->store pairs).
__global__ __launch_bounds__(256) void mb_fused_kernel(
        const float* __restrict__ inputs,
        const int* __restrict__ targets,
        const float* __restrict__ feat_in,
        float* __restrict__ out) {
    __shared__ int4 tg4[NB / 4];   // 16 KB, chain path
    __shared__ int flags[32];      // copy path
    int t = threadIdx.x;

    if (blockIdx.x < CHAIN_BLOCKS) {
        // ---- chain path ----
        #pragma unroll
        for (int k = 0; k < 4; ++k)
            tg4[t + k * 256] =
                reinterpret_cast<const int4*>(targets)[t + k * 256];
        __syncthreads();

        const int* tg = reinterpret_cast<const int*>(tg4);
        int wave = (blockIdx.x * 256 + t) >> 6;   // global sample id
        int lane = t & 63;
        int y = tg[wave];

        // Head check: does y appear at any index < wave? (256 targets/iter)
        for (int base = 0; base < wave; base += 256) {
            int4 v = tg4[(base >> 2) + lane];
            int j0 = base + lane * 4;
            bool m = (j0 < wave && v.x == y) | (j0 + 1 < wave && v.y == y)
                   | (j0 + 2 < wave && v.z == y) | (j0 + 3 < wave && v.w == y);
            if (__ballot(m)) return;  // not the chain head
        }

        // Initial row from ORIGINAL features_memory.
        float4 row = *reinterpret_cast<const float4*>(
            feat_in + (size_t)y * ND + lane * 4);

        // Walk samples j >= wave with targets[j] == y, in index order.
        for (int base = wave & ~255; base < NB; base += 256) {
            int4 v = tg4[(base >> 2) + lane];
            int j0 = base + lane * 4;
            unsigned lm = 0;
            lm |= (j0     >= wave && v.x == y) ? 1u : 0u;
            lm |= (j0 + 1 >= wave && v.y == y) ? 2u : 0u;
            lm |= (j0 + 2 >= wave && v.z == y) ? 4u : 0u;
            lm |= (j0 + 3 >= wave && v.w == y) ? 8u : 0u;
            unsigned long long wm = __ballot(lm != 0);
            while (wm) {
                int L = __ffsll((long long)wm) - 1;
                wm &= wm - 1ull;
                unsigned lmL = (unsigned)__shfl((int)lm, L);
                while (lmL) {
                    int k = __ffs((int)lmL) - 1;
                    lmL &= lmL - 1u;
                    int jj = base + L * 4 + k;
                    float4 x = *reinterpret_cast<const float4*>(
                        inputs + (size_t)jj * ND + lane * 4);
                    row.x = fmaf(MOM, row.x, (1.0f - MOM) * x.x);
                    row.y = fmaf(MOM, row.y, (1.0f - MOM) * x.y);
                    row.z = fmaf(MOM, row.z, (1.0f - MOM) * x.z);
                    row.w = fmaf(MOM, row.w, (1.0f - MOM) * x.w);
                    float ss = row.x * row.x + row.y * row.y
                             + row.z * row.z + row.w * row.w;
                    #pragma unroll
                    for (int off = 32; off > 0; off >>= 1)
                        ss += __shfl_xor(ss, off);
                    float inv = 1.0f / sqrtf(ss);
                    row.x *= inv; row.y *= inv; row.z *= inv; row.w *= inv;
                }
            }
        }

        *reinterpret_cast<float4*>(out + (size_t)y * ND + lane * 4) = row;
    } else {
        // ---- copy path ----
        int cb = blockIdx.x - CHAIN_BLOCKS;
        int r0 = cb * 32;  // first of the 32 rows this block covers

        // Issue ALL 8 data loads first (independent of the scan).
        const f32x4* src = reinterpret_cast<const f32x4*>(feat_in);
        f32x4* dst = reinterpret_cast<f32x4*>(out);
        size_t base = (size_t)cb * 2048 + t;
        f32x4 v0 = src[base];
        f32x4 v1 = src[base + 256];
        f32x4 v2 = src[base + 512];
        f32x4 v3 = src[base + 768];
        f32x4 v4 = src[base + 1024];
        f32x4 v5 = src[base + 1280];
        f32x4 v6 = src[base + 1536];
        f32x4 v7 = src[base + 1792];

        if (t < 32) flags[t] = 0;
        __syncthreads();

        // Target scan overlaps the in-flight data loads.
        const int4* tgg = reinterpret_cast<const int4*>(targets);
        #pragma unroll
        for (int k = 0; k < 4; ++k) {
            int4 v = tgg[t + k * 256];
            if ((unsigned)(v.x - r0) < 32u) flags[v.x - r0] = 1;
            if ((unsigned)(v.y - r0) < 32u) flags[v.y - r0] = 1;
            if ((unsigned)(v.z - r0) < 32u) flags[v.z - r0] = 1;
            if ((unsigned)(v.w - r0) < 32u) flags[v.w - r0] = 1;
        }
        __syncthreads();

        // Pin all 8 values live here: forces unconditional materialization,
        // preventing LLVM from sinking each load into its store branch.
        asm volatile("" : "+v"(v0), "+v"(v1), "+v"(v2), "+v"(v3),
                          "+v"(v4), "+v"(v5), "+v"(v6), "+v"(v7));

        int w = t >> 6;  // local row of access k is w + 4k (wave-uniform)
        if (!flags[w     ]) __builtin_nontemporal_store(v0, dst + base);
        if (!flags[w +  4]) __builtin_nontemporal_store(v1, dst + base + 256);
        if (!flags[w +  8]) __builtin_nontemporal_store(v2, dst + base + 512);
        if (!flags[w + 12]) __builtin_nontemporal_store(v3, dst + base + 768);
        if (!flags[w + 16]) __builtin_nontemporal_store(v4, dst + base + 1024);
        if (!flags[w + 20]) __builtin_nontemporal_store(v5, dst + base + 1280);
        if (!flags[w + 24]) __builtin_nontemporal_store(v6, dst + base + 1536);
        if (!flags[w + 28]) __builtin_nontemporal_store(v7, dst + base + 1792);
    }
}

extern "C" void kernel_launch(void* const* d_in, const int* in_sizes, int n_in,
                              void* d_out, int out_size, void* d_ws, size_t ws_size,
                              hipStream_t stream) {
    const float* inputs  = (const float*)d_in[0];   // [NB, ND]
    const int*   targets = (const int*)d_in[1];     // [NB]
    const float* feat    = (const float*)d_in[2];   // [NC, ND]
    float* out = (float*)d_out;                     // [NC, ND]

    mb_fused_kernel<<<CHAIN_BLOCKS + COPY_BLOCKS, 256, 0, stream>>>(
        inputs, targets, feat, out);
}